// Round 1
// baseline (502.315 us; speedup 1.0000x reference)
//
#include <hip/hip_runtime.h>

#define BB 64
#define MM 512
#define NN 512
#define NUM_SINK 20

// base-2 domain: exp(x) == exp2(x*log2e); K2 = log2(e)/lambda
constexpr float K2     = 1.4426950408889634f / 0.002f;   // ~721.3475
constexpr float NEG_K2 = -K2;

__device__ __forceinline__ float exp2fast(float x) { return __builtin_amdgcn_exp2f(x); }
__device__ __forceinline__ float log2fast(float x) { return __builtin_amdgcn_logf(x); }

// ---------------------------------------------------------------------------
// Column phase: G[b][n] = log2(bmarg[b][n]) - L2SE_m(F[b][m] - c[b][m][n]*K2)
// grid = BB*4 (4 blocks of 128 columns), block = 512 threads.
// Thread t: columns n0 + (t&31)*4 .. +3 (float4), rows [(t>>5)*32, +32).
// ---------------------------------------------------------------------------
__global__ __launch_bounds__(512) void col_kernel(
    const float* __restrict__ c, const float* __restrict__ bmarg,
    const float* __restrict__ F, float* __restrict__ G, int first)
{
    __shared__ float sF[MM];            // F' = F - maxF  (<= 0)
    __shared__ float sPart[16][128];    // per-m-group partial sums
    __shared__ float sRed[8];

    const int b  = blockIdx.x >> 2;
    const int n0 = (blockIdx.x & 3) * 128;
    const int t  = threadIdx.x;

    float maxF = 0.0f;
    float v    = 0.0f;
    if (!first) {
        v = F[b * MM + t];
        float wm = v;
        #pragma unroll
        for (int o = 32; o > 0; o >>= 1) wm = fmaxf(wm, __shfl_xor(wm, o, 64));
        if ((t & 63) == 0) sRed[t >> 6] = wm;
        __syncthreads();
        if (t == 0) {
            float m2 = sRed[0];
            #pragma unroll
            for (int i = 1; i < 8; ++i) m2 = fmaxf(m2, sRed[i]);
            sRed[0] = m2;
        }
        __syncthreads();
        maxF = sRed[0];
    }
    sF[t] = v - maxF;
    __syncthreads();

    const int lane_c = t & 31;          // 32 column-groups of 4 columns
    const int mg     = t >> 5;          // 16 m-groups of 32 rows
    const int n4     = n0 + lane_c * 4;
    const float* cp  = c + (size_t)b * MM * NN;
    const int m0     = mg * 32;

    float s0 = 0.f, s1 = 0.f, s2 = 0.f, s3 = 0.f;
    #pragma unroll 4
    for (int r = 0; r < 32; ++r) {
        const int m = m0 + r;
        const float fp = sF[m];
        const float4 cv = *(const float4*)(cp + (size_t)m * NN + n4);
        s0 += exp2fast(fmaf(cv.x, NEG_K2, fp));
        s1 += exp2fast(fmaf(cv.y, NEG_K2, fp));
        s2 += exp2fast(fmaf(cv.z, NEG_K2, fp));
        s3 += exp2fast(fmaf(cv.w, NEG_K2, fp));
    }
    sPart[mg][lane_c * 4 + 0] = s0;
    sPart[mg][lane_c * 4 + 1] = s1;
    sPart[mg][lane_c * 4 + 2] = s2;
    sPart[mg][lane_c * 4 + 3] = s3;
    __syncthreads();

    if (t < 128) {
        float tot = 0.f;
        #pragma unroll
        for (int g = 0; g < 16; ++g) tot += sPart[g][t];
        const int n = n0 + t;
        G[b * NN + n] = log2fast(bmarg[b * NN + n]) - maxF - log2fast(tot);
    }
}

// ---------------------------------------------------------------------------
// Row phase: F[b][m] = log2(amarg[b][m]) - L2SE_n(G[b][n] - c[b][m][n]*K2)
// If WRITE_OUT, also writes out[b][m][n] = exp2(F_m + G_n - c*K2).
// grid = BB*8 (8 blocks of 64 rows), block = 512 (8 waves, 1 wave per row,
// 8 rows sequentially per wave). Lane reads 2 float4 per row (coalesced 1KB).
// ---------------------------------------------------------------------------
template <bool WRITE_OUT>
__global__ __launch_bounds__(512) void row_kernel(
    const float* __restrict__ c, const float* __restrict__ amarg,
    const float* __restrict__ G, float* __restrict__ F, float* __restrict__ out)
{
    __shared__ float sG[NN];            // G' = G - maxG  (<= 0)
    __shared__ float sRed[8];

    const int b  = blockIdx.x >> 3;
    const int m0 = (blockIdx.x & 7) * 64;
    const int t  = threadIdx.x;

    const float v = G[b * NN + t];
    float wm = v;
    #pragma unroll
    for (int o = 32; o > 0; o >>= 1) wm = fmaxf(wm, __shfl_xor(wm, o, 64));
    if ((t & 63) == 0) sRed[t >> 6] = wm;
    __syncthreads();
    if (t == 0) {
        float m2 = sRed[0];
        #pragma unroll
        for (int i = 1; i < 8; ++i) m2 = fmaxf(m2, sRed[i]);
        sRed[0] = m2;
    }
    __syncthreads();
    const float maxG = sRed[0];
    sG[t] = v - maxG;
    __syncthreads();

    const int wave = t >> 6;            // 8 waves
    const int lane = t & 63;
    const float* cp = c + (size_t)b * MM * NN;
    const int n4a = lane * 4;
    const int n4b = lane * 4 + 256;

    const float4 g0 = *(const float4*)&sG[n4a];
    const float4 g1 = *(const float4*)&sG[n4b];

    #pragma unroll 2
    for (int r = 0; r < 8; ++r) {
        const int m = m0 + wave * 8 + r;
        const float* rowp = cp + (size_t)m * NN;
        const float4 c0 = *(const float4*)(rowp + n4a);
        const float4 c1 = *(const float4*)(rowp + n4b);

        float s = exp2fast(fmaf(c0.x, NEG_K2, g0.x)) + exp2fast(fmaf(c0.y, NEG_K2, g0.y))
                + exp2fast(fmaf(c0.z, NEG_K2, g0.z)) + exp2fast(fmaf(c0.w, NEG_K2, g0.w))
                + exp2fast(fmaf(c1.x, NEG_K2, g1.x)) + exp2fast(fmaf(c1.y, NEG_K2, g1.y))
                + exp2fast(fmaf(c1.z, NEG_K2, g1.z)) + exp2fast(fmaf(c1.w, NEG_K2, g1.w));
        #pragma unroll
        for (int o = 32; o > 0; o >>= 1) s += __shfl_xor(s, o, 64);

        const float Fm = log2fast(amarg[b * MM + m]) - maxG - log2fast(s);
        if (lane == 0) F[b * MM + m] = Fm;

        if (WRITE_OUT) {
            const float base = Fm + maxG;   // out = exp2(base + G'_n - c*K2)
            float4 o0, o1;
            o0.x = exp2fast(fmaf(c0.x, NEG_K2, base + g0.x));
            o0.y = exp2fast(fmaf(c0.y, NEG_K2, base + g0.y));
            o0.z = exp2fast(fmaf(c0.z, NEG_K2, base + g0.z));
            o0.w = exp2fast(fmaf(c0.w, NEG_K2, base + g0.w));
            o1.x = exp2fast(fmaf(c1.x, NEG_K2, base + g1.x));
            o1.y = exp2fast(fmaf(c1.y, NEG_K2, base + g1.y));
            o1.z = exp2fast(fmaf(c1.z, NEG_K2, base + g1.z));
            o1.w = exp2fast(fmaf(c1.w, NEG_K2, base + g1.w));
            float* op = out + (size_t)b * MM * NN + (size_t)m * NN;
            *(float4*)(op + n4a) = o0;
            *(float4*)(op + n4b) = o1;
        }
    }
}

extern "C" void kernel_launch(void* const* d_in, const int* in_sizes, int n_in,
                              void* d_out, int out_size, void* d_ws, size_t ws_size,
                              hipStream_t stream) {
    const float* c  = (const float*)d_in[0];
    const float* a  = (const float*)d_in[1];
    const float* bm = (const float*)d_in[2];
    float* out = (float*)d_out;

    float* F = (float*)d_ws;            // [BB][MM]  (128 KB)
    float* G = F + BB * MM;             // [BB][NN]  (128 KB)

    for (int it = 0; it < NUM_SINK; ++it) {
        hipLaunchKernelGGL(col_kernel, dim3(BB * 4), dim3(512), 0, stream,
                           c, bm, F, G, it == 0 ? 1 : 0);
        if (it < NUM_SINK - 1)
            hipLaunchKernelGGL(row_kernel<false>, dim3(BB * 8), dim3(512), 0, stream,
                               c, a, G, F, out);
        else
            hipLaunchKernelGGL(row_kernel<true>, dim3(BB * 8), dim3(512), 0, stream,
                               c, a, G, F, out);
    }
}